// Round 7
// baseline (704.191 us; speedup 1.0000x reference)
//
#include <hip/hip_runtime.h>
#include <math.h>

typedef unsigned short u16;
typedef unsigned int   u32;
typedef float  v16f __attribute__((ext_vector_type(16)));
typedef short  v8s  __attribute__((ext_vector_type(8)));

__device__ __forceinline__ float sigf(float x) { return 1.0f / (1.0f + __expf(-x)); }
__device__ __forceinline__ float tanhfast(float x) { return 2.0f / (1.0f + __expf(-2.0f * x)) - 1.0f; }
__device__ __forceinline__ u16 f2bf(float f) {
    u32 x = __float_as_uint(f);
    u32 r = (x + 0x7fffu + ((x >> 16) & 1u)) >> 16;   // RNE
    return (u16)r;
}

// ---------------------------------------------------------------------
// Conv-as-MFMA constants (verified R4)
// ---------------------------------------------------------------------
#define KE        19
#define SLAB      2048
#define G0_OFF    0
#define G1_OFF    (3 * KE * SLAB)
#define G2_OFF    (7 * KE * SLAB)
#define WKR_TOT   (12 * KE * SLAB)
#define XSTR      312

__global__ __launch_bounds__(256) void k_cprep(const float* __restrict__ w3,
                                               const float* __restrict__ w4,
                                               const float* __restrict__ w5,
                                               u16* __restrict__ wkr) {
    const int gid = blockIdx.x * 256 + threadIdx.x;
    int g, rem;
    if (gid < G1_OFF)      { g = 0; rem = gid; }
    else if (gid < G2_OFF) { g = 1; rem = gid - G1_OFF; }
    else                   { g = 2; rem = gid - G2_OFF; }
    const int fs = 3 + g;
    const int j  = rem & 7;
    const int q  = (rem >> 3) & 1;
    const int f  = (rem >> 4) & 127;
    const int t  = rem >> 11;
    const int ke = t % KE;
    const int kk = t / KE;
    const int e  = ke * 16 + q * 8 + j;
    float v = 0.0f;
    if (f < 100 && e < 300) {
        const float* w = (g == 0) ? w3 : (g == 1) ? w4 : w5;
        v = w[((size_t)f * 300 + e) * fs + kk];
    }
    wkr[gid] = f2bf(v);
}

// =====================================================================
// K1: conv via MFMA (unchanged from R4)
// =====================================================================
__global__ __launch_bounds__(384) void k_conv_mfma(const int* __restrict__ dlg,
                                                   const float* __restrict__ emb,
                                                   const u16* __restrict__ wkr,
                                                   const float* __restrict__ b3,
                                                   const float* __restrict__ b4,
                                                   const float* __restrict__ b5,
                                                   float* __restrict__ feat) {
    __shared__ u16 xT[104 * XSTR];
    __shared__ int toks[96];
    const int u2  = blockIdx.x;
    const int tid = threadIdx.x;
    if (tid < 96) toks[tid] = dlg[u2 * 96 + tid];
    __syncthreads();
    for (int i = tid; i < 96 * 75; i += 384) {
        int t  = i / 75;
        int e4 = i - t * 75;
        int utt = (t >= 48);
        int row = utt * 52 + (t - utt * 48);
        float4 v = *(const float4*)(emb + (size_t)toks[t] * 300 + e4 * 4);
        uint2 o;
        o.x = (u32)f2bf(v.x) | ((u32)f2bf(v.y) << 16);
        o.y = (u32)f2bf(v.z) | ((u32)f2bf(v.w) << 16);
        *(uint2*)&xT[row * XSTR + e4 * 4] = o;
    }
    for (int i = tid; i < 8 * (XSTR / 2); i += 384) {
        int r = i / (XSTR / 2);
        int c = i - r * (XSTR / 2);
        int row = (r < 4) ? (48 + r) : (96 + r - 4);
        *(u32*)&xT[row * XSTR + c * 2] = 0;
    }
    __syncthreads();

    const int wv   = tid >> 6;
    const int lane = tid & 63;
    const int m    = lane & 31;
    const int q    = lane >> 5;

    int abase[3];
#pragma unroll
    for (int mt = 0; mt < 3; ++mt) {
        int r = mt * 32 + m;
        int utt = (r >= 48);
        int p = r - utt * 48;
        abase[mt] = (utt * 52 + p) * XSTR + q * 8;
    }

    int gA, ntA, gB, ntB, kkA, kkB;
    if (wv < 4) { gA = 0; ntA = wv; gB = 2; ntB = wv; kkA = 3; kkB = 5; }
    else        { gA = 1; ntA = (wv - 4) * 2; gB = 1; ntB = ntA + 1; kkA = 4; kkB = 4; }
    const int kkmax = (kkA > kkB) ? kkA : kkB;
    const int goffA = (gA == 0) ? G0_OFF : (gA == 1) ? G1_OFF : G2_OFF;
    const int goffB = (gB == 0) ? G0_OFF : (gB == 1) ? G1_OFF : G2_OFF;
    const u16* wA = wkr + goffA + ((ntA * 32 + m) * 2 + q) * 8;
    const u16* wB = wkr + goffB + ((ntB * 32 + m) * 2 + q) * 8;

    v16f accA[3], accB[3];
#pragma unroll
    for (int mt = 0; mt < 3; ++mt) {
#pragma unroll
        for (int r = 0; r < 16; ++r) { accA[mt][r] = 0.0f; accB[mt][r] = 0.0f; }
    }

    for (int kk = 0; kk < kkmax; ++kk) {
        const bool doA = (kk < kkA);
        const bool doB = (kk < kkB);
        const int xshift = kk * XSTR;
        for (int ke = 0; ke < KE; ++ke) {
            v8s bfA, bfB;
            if (doA) bfA = *(const v8s*)(wA + (kk * KE + ke) * SLAB);
            if (doB) bfB = *(const v8s*)(wB + (kk * KE + ke) * SLAB);
            const int xcol = ke * 16;
#pragma unroll
            for (int mt = 0; mt < 3; ++mt) {
                v8s af = *(const v8s*)&xT[abase[mt] + xshift + xcol];
                if (doA) accA[mt] = __builtin_amdgcn_mfma_f32_32x32x16_bf16(af, bfA, accA[mt], 0, 0, 0);
                if (doB) accB[mt] = __builtin_amdgcn_mfma_f32_32x32x16_bf16(af, bfB, accB[mt], 0, 0, 0);
            }
        }
    }

    const int PP[3] = {46, 45, 44};
#pragma unroll
    for (int which = 0; which < 2; ++which) {
        const int g  = which ? gB : gA;
        const int nt = which ? ntB : ntA;
        const v16f* acc = which ? accB : accA;
        const float* bg = (g == 0) ? b3 : (g == 1) ? b4 : b5;
        const int f = nt * 32 + m;
        const float bias = (f < 100) ? bg[f] : 0.0f;
        const int Pg = PP[g];
        float v0 = -1e30f, v1 = -1e30f;
#pragma unroll
        for (int mt = 0; mt < 3; ++mt) {
#pragma unroll
            for (int reg = 0; reg < 16; ++reg) {
                int row = (reg & 3) + 8 * (reg >> 2) + 4 * q;
                int r = mt * 32 + row;
                int utt = (r >= 48);
                int p = r - utt * 48;
                if (p < Pg) {
                    float val = acc[mt][reg] + bias;
                    if (utt) v1 = fmaxf(v1, val); else v0 = fmaxf(v0, val);
                }
            }
        }
        v0 = fmaxf(v0, __shfl_xor(v0, 32, 64));
        v1 = fmaxf(v1, __shfl_xor(v1, 32, 64));
        if (q == 0 && f < 100) {
            feat[((size_t)(u2 * 2 + 0)) * 300 + g * 100 + f] = fmaxf(0.0f, v0);
            feat[((size_t)(u2 * 2 + 1)) * 300 + g * 100 + f] = fmaxf(0.0f, v1);
        }
    }
}

// =====================================================================
// K2: xg GEMM; output in MFMA C-fragment order (unchanged from R6)
// =====================================================================
__global__ __launch_bounds__(256) void k_xg(const float* __restrict__ feat,
                                            const float* __restrict__ wih_f, const float* __restrict__ bih_f,
                                            const float* __restrict__ bhh_f,
                                            const float* __restrict__ wih_r, const float* __restrict__ bih_r,
                                            const float* __restrict__ bhh_r,
                                            float* __restrict__ xgF) {
    __shared__ float fls[300 * 36];
    const int bx  = blockIdx.x;
    const int dir = bx >> 8;
    const int t   = (bx >> 2) & 63;
    const int gc  = bx & 3;
    const int tid = threadIdx.x;
    for (int i = tid; i < 32 * 300; i += 256) {
        int b = i / 300;
        int d = i - b * 300;
        fls[d * 36 + b] = feat[((size_t)b * 64 + t) * 300 + d];
    }
    __syncthreads();
    const int g = gc * 256 + tid;
    const float* wih = dir ? wih_r : wih_f;
    const float* bih = dir ? bih_r : bih_f;
    const float* bhh = dir ? bhh_r : bhh_f;
    const float* wr  = wih + (size_t)g * 300;
    const float bias = bih[g] + bhh[g];
    float acc[32];
#pragma unroll
    for (int b = 0; b < 32; ++b) acc[b] = 0.0f;
    for (int d = 0; d < 300; d += 4) {
        float4 wv = *(const float4*)(wr + d);
#pragma unroll
        for (int j = 0; j < 4; ++j) {
            float w = (j == 0) ? wv.x : (j == 1) ? wv.y : (j == 2) ? wv.z : wv.w;
            const float* r = &fls[(d + j) * 36];
#pragma unroll
            for (int bq = 0; bq < 8; ++bq) {
                float4 x = *(const float4*)(r + bq * 4);
                acc[bq * 4 + 0] = fmaf(w, x.x, acc[bq * 4 + 0]);
                acc[bq * 4 + 1] = fmaf(w, x.y, acc[bq * 4 + 1]);
                acc[bq * 4 + 2] = fmaf(w, x.z, acc[bq * 4 + 2]);
                acc[bq * 4 + 3] = fmaf(w, x.w, acc[bq * 4 + 3]);
            }
        }
    }
    const int jj      = tid;
    const int js      = jj >> 6;
    const int n_local = ((jj & 63) << 2) | gc;
    const int nt      = n_local >> 5;
    const int lane_lo = n_local & 31;
    float* base = xgF + (((size_t)(dir * 64 + t) * 32) + js * 8 + nt) * 1024;
#pragma unroll
    for (int b = 0; b < 32; ++b) {
        int q    = (b >> 2) & 1;
        int reg  = (b & 3) + ((b >> 3) << 2);
        base[reg * 64 + lane_lo + (q << 5)] = acc[b] + bias;
    }
}

// =====================================================================
// K_prep3: w_hh -> MFMA B-fragment shards (unchanged from R6)
// =====================================================================
__global__ __launch_bounds__(256) void k_prep3(const float* __restrict__ whh_f,
                                               const float* __restrict__ whh_r,
                                               u16* __restrict__ wpk3) {
    const int gid  = blockIdx.x * 256 + threadIdx.x;    // [0, 524288)
    const int j    = gid & 7;
    const int lane = (gid >> 3) & 63;
    const int kt   = (gid >> 9) & 15;
    const int nt   = (gid >> 13) & 7;
    const int js   = (gid >> 16) & 3;
    const int dir  = (gid >> 18) & 1;
    const int n_local = nt * 32 + (lane & 31);
    const int jjl  = n_local >> 2;
    const int gate = n_local & 3;
    const int k    = kt * 16 + (lane >> 5) * 8 + j;
    const int row  = gate * 256 + js * 64 + jjl;
    const float* whh = dir ? whh_r : whh_f;
    wpk3[gid] = f2bf(whh[(size_t)row * 256 + k]);
}

// k_init: zero hxT (tag 0 | bf16(0) everywhere)
__global__ __launch_bounds__(256) void k_init(u32* __restrict__ hxT) {
    const int i = blockIdx.x * 256 + threadIdx.x;
    if (i < 32768) hxT[i] = 0u;   // 2 dir x 2 slot x 256 k x 32 b
}

// =====================================================================
// K3 v3: LSTM, 8 blocks (2 dir x 4 js), MFMA, FENCE-FREE tagged h exchange.
// hxT[dir][slot][k(256)][b(32)] u32 = (tag<<16)|bf16(h). Iter s consumes
// tag s from slot s&1, produces tag s+1 into slot (s+1)&1. Relaxed
// agent-scope atomics only — no fences, no flags, no L2 flush/inv.
// =====================================================================
__global__ __launch_bounds__(512) void k_lstm2(const u16* __restrict__ wpk3,
                                               const float* __restrict__ xgF,
                                               u32* __restrict__ hxT,
                                               float* __restrict__ hseq) {
    __shared__ float gbuf[32 * 276];
    const int dir = blockIdx.x >> 2;
    const int js  = blockIdx.x & 3;
    const int tid = threadIdx.x;
    const int w   = tid >> 6;                 // n-tile 0..7
    const int l   = tid & 63;
    const int m   = l & 31;
    const int q   = l >> 5;

    // preload B fragments (16 kt x 4 VGPR)
    v8s Bf[16];
    {
        const u16* wb = wpk3 + ((((size_t)dir * 4 + js) * 8 + w) * 16) * 512 + (size_t)l * 8;
#pragma unroll
        for (int kt = 0; kt < 16; ++kt) Bf[kt] = *(const v8s*)(wb + kt * 512);
    }

    const int eb  = tid & 31;
    const int ejb = tid >> 5;                 // 0..15
    float cst[4];
#pragma unroll
    for (int c2 = 0; c2 < 4; ++c2) cst[c2] = 0.0f;

    float* hout = hseq + (size_t)dir * 64 * 32 * 256;
    u32* hx_base = hxT + (size_t)dir * 2 * 8192;

    for (int s = 0; s < 64; ++s) {
        const int t = dir ? (63 - s) : s;
        // acc init from xgF (independent of sync — issued early)
        v16f acc;
        const float* xb = xgF + (((size_t)(dir * 64 + t) * 32) + js * 8 + w) * 1024 + l;
#pragma unroll
        for (int r = 0; r < 16; ++r) acc[r] = xb[r * 64];

        u32* hxs = hx_base + (size_t)(s & 1) * 8192;
        const u32 want = (u32)s;

        // 4 chunks of 4 kt: poll 32 tagged values, then 4 MFMAs
#pragma unroll
        for (int kc = 0; kc < 4; ++kc) {
            u32 hv[32];
            u32 guard = 0;
            for (;;) {
                bool ok = true;
#pragma unroll
                for (int k2 = 0; k2 < 4; ++k2) {
                    const int kt = kc * 4 + k2;
#pragma unroll
                    for (int j = 0; j < 8; ++j) {
                        hv[k2 * 8 + j] = __hip_atomic_load(
                            &hxs[(kt * 16 + q * 8 + j) * 32 + m],
                            __ATOMIC_RELAXED, __HIP_MEMORY_SCOPE_AGENT);
                    }
                }
#pragma unroll
                for (int i = 0; i < 32; ++i) ok &= ((hv[i] >> 16) == want);
                if (ok || ++guard > (1u << 18)) break;
                __builtin_amdgcn_s_sleep(1);
            }
#pragma unroll
            for (int k2 = 0; k2 < 4; ++k2) {
                const int kt = kc * 4 + k2;
                union { v8s v; u16 a[8]; } af;
#pragma unroll
                for (int j = 0; j < 8; ++j) af.a[j] = (u16)hv[k2 * 8 + j];
                acc = __builtin_amdgcn_mfma_f32_32x32x16_bf16(af.v, Bf[kt], acc, 0, 0, 0);
            }
        }

        // gate preacts -> LDS
#pragma unroll
        for (int r = 0; r < 16; ++r) {
            int row = (r & 3) + 8 * (r >> 2) + 4 * q;
            gbuf[row * 276 + w * 32 + m] = acc[r];
        }
        __syncthreads();

        // combine gates
        float hval[4];
        {
            const float* gb = &gbuf[eb * 276 + ejb * 16];
#pragma unroll
            for (int c2 = 0; c2 < 4; ++c2) {
                float4 gv = *(const float4*)(gb + c2 * 4);
                float i_ = sigf(gv.x), f_ = sigf(gv.y);
                float g_ = tanhfast(gv.z), o_ = sigf(gv.w);
                cst[c2] = f_ * cst[c2] + i_ * g_;
                hval[c2] = o_ * tanhfast(cst[c2]);
            }
        }
        // write h: hseq (fp32) + tagged hxT slot (s+1)&1
        {
            float4 hv4 = make_float4(hval[0], hval[1], hval[2], hval[3]);
            *(float4*)&hout[((size_t)t * 32 + eb) * 256 + js * 64 + ejb * 4] = hv4;
            u32* hxn = hx_base + (size_t)((s + 1) & 1) * 8192;
            const u32 ntag = (u32)(s + 1) << 16;
#pragma unroll
            for (int c2 = 0; c2 < 4; ++c2) {
                const int k = js * 64 + ejb * 4 + c2;
                __hip_atomic_store(&hxn[k * 32 + eb], ntag | (u32)f2bf(hval[c2]),
                                   __ATOMIC_RELAXED, __HIP_MEMORY_SCOPE_AGENT);
            }
        }
        __syncthreads();   // gbuf reuse next iteration
    }
}

// =====================================================================
// K4: head (unchanged)
// =====================================================================
__global__ __launch_bounds__(256) void k_head(const float* __restrict__ hseq,
                                              const float* __restrict__ hw,
                                              const float* __restrict__ hb,
                                              float* __restrict__ out) {
    const int id = blockIdx.x * 256 + threadIdx.x;
    const int o  = id & 31;
    const int u  = id >> 5;
    const int b  = u >> 6, t = u & 63;
    const float* pf = hseq + ((size_t)t * 32 + b) * 256;
    const float* pr = hseq + (size_t)64 * 32 * 256 + ((size_t)t * 32 + b) * 256;
    const float* wo = hw + (size_t)o * 512;
    float acc = hb[o];
    for (int j = 0; j < 256; j += 4) {
        float4 wa = *(const float4*)(wo + j);
        float4 wb = *(const float4*)(wo + 256 + j);
        float4 fa = *(const float4*)(pf + j);
        float4 fb = *(const float4*)(pr + j);
        acc = fmaf(wa.x, fa.x, acc); acc = fmaf(wa.y, fa.y, acc);
        acc = fmaf(wa.z, fa.z, acc); acc = fmaf(wa.w, fa.w, acc);
        acc = fmaf(wb.x, fb.x, acc); acc = fmaf(wb.y, fb.y, acc);
        acc = fmaf(wb.z, fb.z, acc); acc = fmaf(wb.w, fb.w, acc);
    }
    out[id] = sigf(acc);
}

// =====================================================================
extern "C" void kernel_launch(void* const* d_in, const int* in_sizes, int n_in,
                              void* d_out, int out_size, void* d_ws, size_t ws_size,
                              hipStream_t stream) {
    const int*   dlg   = (const int*)d_in[0];
    const float* emb   = (const float*)d_in[1];
    const float* w3    = (const float*)d_in[2];  const float* b3    = (const float*)d_in[3];
    const float* w4    = (const float*)d_in[4];  const float* b4    = (const float*)d_in[5];
    const float* w5    = (const float*)d_in[6];  const float* b5    = (const float*)d_in[7];
    const float* wih_f = (const float*)d_in[8];  const float* whh_f = (const float*)d_in[9];
    const float* bih_f = (const float*)d_in[10]; const float* bhh_f = (const float*)d_in[11];
    const float* wih_r = (const float*)d_in[12]; const float* whh_r = (const float*)d_in[13];
    const float* bih_r = (const float*)d_in[14]; const float* bhh_r = (const float*)d_in[15];
    const float* hw    = (const float*)d_in[16]; const float* hb    = (const float*)d_in[17];
    float* out = (float*)d_out;

    float* f     = (float*)d_ws;
    float* feat  = f;                         // 614400
    float* xgF   = f + 614400;                // 4194304
    float* hseq  = f + 4808704;               // 1048576
    u16*   wkr   = (u16*)(f + 5857280);       // 466944 u16
    u16*   wpk3  = (u16*)(f + 6090752);       // 524288 u16
    u32*   hxT   = (u32*)(f + 6352896);       // 32768 u32 (2 dir x 2 slot x 8192)
    // total ~25.6 MB

    hipLaunchKernelGGL(k_init, dim3(128), dim3(256), 0, stream, hxT);
    hipLaunchKernelGGL(k_cprep, dim3(WKR_TOT / 256), dim3(256), 0, stream,
                       w3, w4, w5, wkr);
    hipLaunchKernelGGL(k_prep3, dim3(2048), dim3(256), 0, stream,
                       whh_f, whh_r, wpk3);
    hipLaunchKernelGGL(k_conv_mfma, dim3(1024), dim3(384), 0, stream,
                       dlg, emb, wkr, b3, b4, b5, feat);
    hipLaunchKernelGGL(k_xg, dim3(512), dim3(256), 0, stream,
                       feat, wih_f, bih_f, bhh_f, wih_r, bih_r, bhh_r, xgF);
    hipLaunchKernelGGL(k_lstm2, dim3(8), dim3(512), 0, stream,
                       wpk3, xgF, hxT, hseq);
    hipLaunchKernelGGL(k_head, dim3(256), dim3(256), 0, stream,
                       hseq, hw, hb, out);
}

// Round 9
// 599.781 us; speedup vs baseline: 1.1741x; 1.1741x over previous
//
#include <hip/hip_runtime.h>
#include <math.h>

typedef unsigned short u16;
typedef unsigned int   u32;
typedef unsigned long long u64;
typedef float  v16f __attribute__((ext_vector_type(16)));
typedef short  v8s  __attribute__((ext_vector_type(8)));

__device__ __forceinline__ float sigf(float x) { return 1.0f / (1.0f + __expf(-x)); }
__device__ __forceinline__ float tanhfast(float x) { return 2.0f / (1.0f + __expf(-2.0f * x)) - 1.0f; }
__device__ __forceinline__ u16 f2bf(float f) {
    u32 x = __float_as_uint(f);
    u32 r = (x + 0x7fffu + ((x >> 16) & 1u)) >> 16;   // RNE
    return (u16)r;
}

// ---------------------------------------------------------------------
// Conv-as-MFMA constants (verified R4)
// ---------------------------------------------------------------------
#define KE        19
#define SLAB      2048
#define G0_OFF    0
#define G1_OFF    (3 * KE * SLAB)
#define G2_OFF    (7 * KE * SLAB)
#define WKR_TOT   (12 * KE * SLAB)
#define XSTR      312

__global__ __launch_bounds__(256) void k_cprep(const float* __restrict__ w3,
                                               const float* __restrict__ w4,
                                               const float* __restrict__ w5,
                                               u16* __restrict__ wkr) {
    const int gid = blockIdx.x * 256 + threadIdx.x;
    int g, rem;
    if (gid < G1_OFF)      { g = 0; rem = gid; }
    else if (gid < G2_OFF) { g = 1; rem = gid - G1_OFF; }
    else                   { g = 2; rem = gid - G2_OFF; }
    const int fs = 3 + g;
    const int j  = rem & 7;
    const int q  = (rem >> 3) & 1;
    const int f  = (rem >> 4) & 127;
    const int t  = rem >> 11;
    const int ke = t % KE;
    const int kk = t / KE;
    const int e  = ke * 16 + q * 8 + j;
    float v = 0.0f;
    if (f < 100 && e < 300) {
        const float* w = (g == 0) ? w3 : (g == 1) ? w4 : w5;
        v = w[((size_t)f * 300 + e) * fs + kk];
    }
    wkr[gid] = f2bf(v);
}

// =====================================================================
// K1: conv via MFMA (unchanged from R4)
// =====================================================================
__global__ __launch_bounds__(384) void k_conv_mfma(const int* __restrict__ dlg,
                                                   const float* __restrict__ emb,
                                                   const u16* __restrict__ wkr,
                                                   const float* __restrict__ b3,
                                                   const float* __restrict__ b4,
                                                   const float* __restrict__ b5,
                                                   float* __restrict__ feat) {
    __shared__ u16 xT[104 * XSTR];
    __shared__ int toks[96];
    const int u2  = blockIdx.x;
    const int tid = threadIdx.x;
    if (tid < 96) toks[tid] = dlg[u2 * 96 + tid];
    __syncthreads();
    for (int i = tid; i < 96 * 75; i += 384) {
        int t  = i / 75;
        int e4 = i - t * 75;
        int utt = (t >= 48);
        int row = utt * 52 + (t - utt * 48);
        float4 v = *(const float4*)(emb + (size_t)toks[t] * 300 + e4 * 4);
        uint2 o;
        o.x = (u32)f2bf(v.x) | ((u32)f2bf(v.y) << 16);
        o.y = (u32)f2bf(v.z) | ((u32)f2bf(v.w) << 16);
        *(uint2*)&xT[row * XSTR + e4 * 4] = o;
    }
    for (int i = tid; i < 8 * (XSTR / 2); i += 384) {
        int r = i / (XSTR / 2);
        int c = i - r * (XSTR / 2);
        int row = (r < 4) ? (48 + r) : (96 + r - 4);
        *(u32*)&xT[row * XSTR + c * 2] = 0;
    }
    __syncthreads();

    const int wv   = tid >> 6;
    const int lane = tid & 63;
    const int m    = lane & 31;
    const int q    = lane >> 5;

    int abase[3];
#pragma unroll
    for (int mt = 0; mt < 3; ++mt) {
        int r = mt * 32 + m;
        int utt = (r >= 48);
        int p = r - utt * 48;
        abase[mt] = (utt * 52 + p) * XSTR + q * 8;
    }

    int gA, ntA, gB, ntB, kkA, kkB;
    if (wv < 4) { gA = 0; ntA = wv; gB = 2; ntB = wv; kkA = 3; kkB = 5; }
    else        { gA = 1; ntA = (wv - 4) * 2; gB = 1; ntB = ntA + 1; kkA = 4; kkB = 4; }
    const int kkmax = (kkA > kkB) ? kkA : kkB;
    const int goffA = (gA == 0) ? G0_OFF : (gA == 1) ? G1_OFF : G2_OFF;
    const int goffB = (gB == 0) ? G0_OFF : (gB == 1) ? G1_OFF : G2_OFF;
    const u16* wA = wkr + goffA + ((ntA * 32 + m) * 2 + q) * 8;
    const u16* wB = wkr + goffB + ((ntB * 32 + m) * 2 + q) * 8;

    v16f accA[3], accB[3];
#pragma unroll
    for (int mt = 0; mt < 3; ++mt) {
#pragma unroll
        for (int r = 0; r < 16; ++r) { accA[mt][r] = 0.0f; accB[mt][r] = 0.0f; }
    }

    for (int kk = 0; kk < kkmax; ++kk) {
        const bool doA = (kk < kkA);
        const bool doB = (kk < kkB);
        const int xshift = kk * XSTR;
        for (int ke = 0; ke < KE; ++ke) {
            v8s bfA, bfB;
            if (doA) bfA = *(const v8s*)(wA + (kk * KE + ke) * SLAB);
            if (doB) bfB = *(const v8s*)(wB + (kk * KE + ke) * SLAB);
            const int xcol = ke * 16;
#pragma unroll
            for (int mt = 0; mt < 3; ++mt) {
                v8s af = *(const v8s*)&xT[abase[mt] + xshift + xcol];
                if (doA) accA[mt] = __builtin_amdgcn_mfma_f32_32x32x16_bf16(af, bfA, accA[mt], 0, 0, 0);
                if (doB) accB[mt] = __builtin_amdgcn_mfma_f32_32x32x16_bf16(af, bfB, accB[mt], 0, 0, 0);
            }
        }
    }

    const int PP[3] = {46, 45, 44};
#pragma unroll
    for (int which = 0; which < 2; ++which) {
        const int g  = which ? gB : gA;
        const int nt = which ? ntB : ntA;
        const v16f* acc = which ? accB : accA;
        const float* bg = (g == 0) ? b3 : (g == 1) ? b4 : b5;
        const int f = nt * 32 + m;
        const float bias = (f < 100) ? bg[f] : 0.0f;
        const int Pg = PP[g];
        float v0 = -1e30f, v1 = -1e30f;
#pragma unroll
        for (int mt = 0; mt < 3; ++mt) {
#pragma unroll
            for (int reg = 0; reg < 16; ++reg) {
                int row = (reg & 3) + 8 * (reg >> 2) + 4 * q;
                int r = mt * 32 + row;
                int utt = (r >= 48);
                int p = r - utt * 48;
                if (p < Pg) {
                    float val = acc[mt][reg] + bias;
                    if (utt) v1 = fmaxf(v1, val); else v0 = fmaxf(v0, val);
                }
            }
        }
        v0 = fmaxf(v0, __shfl_xor(v0, 32, 64));
        v1 = fmaxf(v1, __shfl_xor(v1, 32, 64));
        if (q == 0 && f < 100) {
            feat[((size_t)(u2 * 2 + 0)) * 300 + g * 100 + f] = fmaxf(0.0f, v0);
            feat[((size_t)(u2 * 2 + 1)) * 300 + g * 100 + f] = fmaxf(0.0f, v1);
        }
    }
}

// =====================================================================
// K2: xg GEMM; output in MFMA C-fragment order (unchanged)
// =====================================================================
__global__ __launch_bounds__(256) void k_xg(const float* __restrict__ feat,
                                            const float* __restrict__ wih_f, const float* __restrict__ bih_f,
                                            const float* __restrict__ bhh_f,
                                            const float* __restrict__ wih_r, const float* __restrict__ bih_r,
                                            const float* __restrict__ bhh_r,
                                            float* __restrict__ xgF) {
    __shared__ float fls[300 * 36];
    const int bx  = blockIdx.x;
    const int dir = bx >> 8;
    const int t   = (bx >> 2) & 63;
    const int gc  = bx & 3;
    const int tid = threadIdx.x;
    for (int i = tid; i < 32 * 300; i += 256) {
        int b = i / 300;
        int d = i - b * 300;
        fls[d * 36 + b] = feat[((size_t)b * 64 + t) * 300 + d];
    }
    __syncthreads();
    const int g = gc * 256 + tid;
    const float* wih = dir ? wih_r : wih_f;
    const float* bih = dir ? bih_r : bih_f;
    const float* bhh = dir ? bhh_r : bhh_f;
    const float* wr  = wih + (size_t)g * 300;
    const float bias = bih[g] + bhh[g];
    float acc[32];
#pragma unroll
    for (int b = 0; b < 32; ++b) acc[b] = 0.0f;
    for (int d = 0; d < 300; d += 4) {
        float4 wv = *(const float4*)(wr + d);
#pragma unroll
        for (int j = 0; j < 4; ++j) {
            float w = (j == 0) ? wv.x : (j == 1) ? wv.y : (j == 2) ? wv.z : wv.w;
            const float* r = &fls[(d + j) * 36];
#pragma unroll
            for (int bq = 0; bq < 8; ++bq) {
                float4 x = *(const float4*)(r + bq * 4);
                acc[bq * 4 + 0] = fmaf(w, x.x, acc[bq * 4 + 0]);
                acc[bq * 4 + 1] = fmaf(w, x.y, acc[bq * 4 + 1]);
                acc[bq * 4 + 2] = fmaf(w, x.z, acc[bq * 4 + 2]);
                acc[bq * 4 + 3] = fmaf(w, x.w, acc[bq * 4 + 3]);
            }
        }
    }
    const int jj      = tid;
    const int js      = jj >> 6;
    const int n_local = ((jj & 63) << 2) | gc;
    const int nt      = n_local >> 5;
    const int lane_lo = n_local & 31;
    float* base = xgF + (((size_t)(dir * 64 + t) * 32) + js * 8 + nt) * 1024;
#pragma unroll
    for (int b = 0; b < 32; ++b) {
        int q    = (b >> 2) & 1;
        int reg  = (b & 3) + ((b >> 3) << 2);
        base[reg * 64 + lane_lo + (q << 5)] = acc[b] + bias;
    }
}

// =====================================================================
// K_prep3: w_hh -> MFMA B-fragment shards (unchanged)
// =====================================================================
__global__ __launch_bounds__(256) void k_prep3(const float* __restrict__ whh_f,
                                               const float* __restrict__ whh_r,
                                               u16* __restrict__ wpk3) {
    const int gid  = blockIdx.x * 256 + threadIdx.x;    // [0, 524288)
    const int j    = gid & 7;
    const int lane = (gid >> 3) & 63;
    const int kt   = (gid >> 9) & 15;
    const int nt   = (gid >> 13) & 7;
    const int js   = (gid >> 16) & 3;
    const int dir  = (gid >> 18) & 1;
    const int n_local = nt * 32 + (lane & 31);
    const int jjl  = n_local >> 2;
    const int gate = n_local & 3;
    const int k    = kt * 16 + (lane >> 5) * 8 + j;
    const int row  = gate * 256 + js * 64 + jjl;
    const float* whh = dir ? whh_r : whh_f;
    wpk3[gid] = f2bf(whh[(size_t)row * 256 + k]);
}

// k_init: zero the 8 sentinels
__global__ __launch_bounds__(64) void k_init(u32* __restrict__ sent) {
    if (threadIdx.x < 8) sent[threadIdx.x] = 0u;
}

// =====================================================================
// K3 v5: LSTM, 8 blocks (2 dir x 4 js), MFMA, minimal-traffic exchange.
// hx[dir][slot][b(32)][k64(64)] u64 (4 bf16 each; 2048 u64/slot).
// Producer: 1 u64 relaxed atomic store/thread at [eb*64 + js*16 + ejb];
// __syncthreads (each wave drains vmcnt before s_barrier) -> tid0 stores
// monotone sentinel. Consumer: 3 lanes poll 3 peer sentinels; one
// cooperative bulk pass (3 coalesced u64 atomic loads/thread) into LDS
// hbuf[b][k] (row stride 132 dw); A-frags via ds_read_b128.
// Overwrite safety: sent[peer]>=s  =>  peer finished staging h^(s-1),
// so slot (s+1)&1 (holding h^(s-1)) is dead before we write h^(s+1).
// =====================================================================
__global__ __launch_bounds__(512) void k_lstm3(const u16* __restrict__ wpk3,
                                               const float* __restrict__ xgF,
                                               u64* __restrict__ hx,
                                               u32* __restrict__ sent,
                                               float* __restrict__ hseq) {
    __shared__ u32   hbuf[32 * 132];          // h as bf16-pairs, row stride 132 dw
    __shared__ float gbuf[32 * 276];          // gate preacts
    const int dir = blockIdx.x >> 2;
    const int js  = blockIdx.x & 3;
    const int tid = threadIdx.x;
    const int w   = tid >> 6;                 // n-tile 0..7
    const int l   = tid & 63;
    const int m   = l & 31;
    const int q   = l >> 5;

    // preload B fragments (16 kt x 4 VGPR)
    v8s Bf[16];
    {
        const u16* wb = wpk3 + ((((size_t)dir * 4 + js) * 8 + w) * 16) * 512 + (size_t)l * 8;
#pragma unroll
        for (int kt = 0; kt < 16; ++kt) Bf[kt] = *(const v8s*)(wb + kt * 512);
    }

    const int eb  = tid & 31;                 // owned batch row
    const int ejb = tid >> 5;                 // owned local-j quad 0..15
    float cst[4], hval[4];
#pragma unroll
    for (int c2 = 0; c2 < 4; ++c2) { cst[c2] = 0.0f; hval[c2] = 0.0f; }

    float* hout = hseq + (size_t)dir * 64 * 32 * 256;
    u64* hx_d   = hx + (size_t)dir * 2 * 2048;   // per slot: 32 b x 64 u64
    const int peer = (tid < 3) ? (dir * 4 + tid + (tid >= js ? 1 : 0)) : 0;

    for (int s = 0; s < 64; ++s) {
        const int t = dir ? (63 - s) : s;
        // xgF loads issue early (independent of sync)
        v16f acc;
        const float* xb = xgF + (((size_t)(dir * 64 + t) * 32) + js * 8 + w) * 1024 + l;
#pragma unroll
        for (int r = 0; r < 16; ++r) acc[r] = xb[r * 64];

        // --- wait for peers' h^(s) ---
        if (s > 0 && tid < 3) {
            u32 guard = 0;
            while (__hip_atomic_load(&sent[peer], __ATOMIC_RELAXED,
                                     __HIP_MEMORY_SCOPE_AGENT) < (u32)s) {
                __builtin_amdgcn_s_sleep(1);
                if (++guard > (1u << 25)) break;   // no-hang guard
            }
        }
        __syncthreads();                      // B1: poll done

        // --- stage h^(s) into LDS ---
        if (s > 0) {
            const u64* hxs = hx_d + (size_t)(s & 1) * 2048;
#pragma unroll
            for (int i = 0; i < 3; ++i) {
                int flat = i * 512 + tid;     // [0,1536) = 3 peer quarters
                int b    = flat / 48;
                int r    = flat - b * 48;
                int q64  = r + (r >= js * 16 ? 16 : 0);   // skip own quarter
                u64 v = __hip_atomic_load(&hxs[b * 64 + q64],
                                          __ATOMIC_RELAXED, __HIP_MEMORY_SCOPE_AGENT);
                *(u64*)&hbuf[b * 132 + q64 * 2] = v;
            }
        } else {
            for (int i = tid; i < 32 * 132; i += 512) hbuf[i] = 0u;
        }
        // own quarter from registers (h^(s) produced last iteration; zeros at s=0)
        {
            u64 pk = (u64)f2bf(hval[0]) | ((u64)f2bf(hval[1]) << 16)
                   | ((u64)f2bf(hval[2]) << 32) | ((u64)f2bf(hval[3]) << 48);
            *(u64*)&hbuf[eb * 132 + (js * 16 + ejb) * 2] = pk;
        }
        __syncthreads();                      // B2: hbuf ready

        // --- recurrence GEMM: A-frags from LDS ---
#pragma unroll
        for (int kt = 0; kt < 16; ++kt) {
            v8s af = *(const v8s*)&hbuf[m * 132 + kt * 8 + q * 4];
            acc = __builtin_amdgcn_mfma_f32_32x32x16_bf16(af, Bf[kt], acc, 0, 0, 0);
        }

        // gate preacts -> LDS
#pragma unroll
        for (int r = 0; r < 16; ++r) {
            int row = (r & 3) + 8 * (r >> 2) + 4 * q;
            gbuf[row * 276 + w * 32 + m] = acc[r];
        }
        __syncthreads();                      // B3: gbuf ready

        // combine gates: thread owns (b=eb, jjl=ejb*4+c2)
        {
            const float* gb = &gbuf[eb * 276 + ejb * 16];
#pragma unroll
            for (int c2 = 0; c2 < 4; ++c2) {
                float4 gv = *(const float4*)(gb + c2 * 4);
                float i_ = sigf(gv.x), f_ = sigf(gv.y);
                float g_ = tanhfast(gv.z), o_ = sigf(gv.w);
                cst[c2] = f_ * cst[c2] + i_ * g_;
                hval[c2] = o_ * tanhfast(cst[c2]);
            }
        }
        // write h^(s+1): hseq (fp32) + hx slot (s+1)&1 (one u64 atomic)
        {
            float4 hv4 = make_float4(hval[0], hval[1], hval[2], hval[3]);
            *(float4*)&hout[((size_t)t * 32 + eb) * 256 + js * 64 + ejb * 4] = hv4;
            u64 pk = (u64)f2bf(hval[0]) | ((u64)f2bf(hval[1]) << 16)
                   | ((u64)f2bf(hval[2]) << 32) | ((u64)f2bf(hval[3]) << 48);
            u64* hxn = hx_d + (size_t)((s + 1) & 1) * 2048;
            __hip_atomic_store(&hxn[eb * 64 + js * 16 + ejb], pk,
                               __ATOMIC_RELAXED, __HIP_MEMORY_SCOPE_AGENT);
        }
        __syncthreads();                      // B4: all waves' stores drained (vmcnt)
        if (tid == 0) {
            __hip_atomic_store(&sent[dir * 4 + js], (u32)(s + 1),
                               __ATOMIC_RELAXED, __HIP_MEMORY_SCOPE_AGENT);
        }
    }
}

// =====================================================================
// K4: head (unchanged)
// =====================================================================
__global__ __launch_bounds__(256) void k_head(const float* __restrict__ hseq,
                                              const float* __restrict__ hw,
                                              const float* __restrict__ hb,
                                              float* __restrict__ out) {
    const int id = blockIdx.x * 256 + threadIdx.x;
    const int o  = id & 31;
    const int u  = id >> 5;
    const int b  = u >> 6, t = u & 63;
    const float* pf = hseq + ((size_t)t * 32 + b) * 256;
    const float* pr = hseq + (size_t)64 * 32 * 256 + ((size_t)t * 32 + b) * 256;
    const float* wo = hw + (size_t)o * 512;
    float acc = hb[o];
    for (int j = 0; j < 256; j += 4) {
        float4 wa = *(const float4*)(wo + j);
        float4 wb = *(const float4*)(wo + 256 + j);
        float4 fa = *(const float4*)(pf + j);
        float4 fb = *(const float4*)(pr + j);
        acc = fmaf(wa.x, fa.x, acc); acc = fmaf(wa.y, fa.y, acc);
        acc = fmaf(wa.z, fa.z, acc); acc = fmaf(wa.w, fa.w, acc);
        acc = fmaf(wb.x, fb.x, acc); acc = fmaf(wb.y, fb.y, acc);
        acc = fmaf(wb.z, fb.z, acc); acc = fmaf(wb.w, fb.w, acc);
    }
    out[id] = sigf(acc);
}

// =====================================================================
extern "C" void kernel_launch(void* const* d_in, const int* in_sizes, int n_in,
                              void* d_out, int out_size, void* d_ws, size_t ws_size,
                              hipStream_t stream) {
    const int*   dlg   = (const int*)d_in[0];
    const float* emb   = (const float*)d_in[1];
    const float* w3    = (const float*)d_in[2];  const float* b3    = (const float*)d_in[3];
    const float* w4    = (const float*)d_in[4];  const float* b4    = (const float*)d_in[5];
    const float* w5    = (const float*)d_in[6];  const float* b5    = (const float*)d_in[7];
    const float* wih_f = (const float*)d_in[8];  const float* whh_f = (const float*)d_in[9];
    const float* bih_f = (const float*)d_in[10]; const float* bhh_f = (const float*)d_in[11];
    const float* wih_r = (const float*)d_in[12]; const float* whh_r = (const float*)d_in[13];
    const float* bih_r = (const float*)d_in[14]; const float* bhh_r = (const float*)d_in[15];
    const float* hw    = (const float*)d_in[16]; const float* hb    = (const float*)d_in[17];
    float* out = (float*)d_out;

    float* f     = (float*)d_ws;
    float* feat  = f;                         // 614400
    float* xgF   = f + 614400;                // 4194304
    float* hseq  = f + 4808704;               // 1048576
    u16*   wkr   = (u16*)(f + 5857280);       // 466944 u16
    u16*   wpk3  = (u16*)(f + 6090752);       // 524288 u16
    u64*   hx    = (u64*)(f + 6352896);       // 8192 u64 (2 dir x 2 slot x 2048), 8B-aligned
    u32*   sent  = (u32*)(f + 6369280);       // 8 u32
    // total ~25.5 MB

    hipLaunchKernelGGL(k_init, dim3(1), dim3(64), 0, stream, sent);
    hipLaunchKernelGGL(k_cprep, dim3(WKR_TOT / 256), dim3(256), 0, stream,
                       w3, w4, w5, wkr);
    hipLaunchKernelGGL(k_prep3, dim3(2048), dim3(256), 0, stream,
                       whh_f, whh_r, wpk3);
    hipLaunchKernelGGL(k_conv_mfma, dim3(1024), dim3(384), 0, stream,
                       dlg, emb, wkr, b3, b4, b5, feat);
    hipLaunchKernelGGL(k_xg, dim3(512), dim3(256), 0, stream,
                       feat, wih_f, bih_f, bhh_f, wih_r, bih_r, bhh_r, xgF);
    hipLaunchKernelGGL(k_lstm3, dim3(8), dim3(512), 0, stream,
                       wpk3, xgF, hx, sent, hseq);
    hipLaunchKernelGGL(k_head, dim3(256), dim3(256), 0, stream,
                       hseq, hw, hb, out);
}

// Round 11
// 567.722 us; speedup vs baseline: 1.2404x; 1.0565x over previous
//
#include <hip/hip_runtime.h>
#include <math.h>

typedef unsigned short u16;
typedef unsigned int   u32;
typedef unsigned long long u64;
typedef float  v16f __attribute__((ext_vector_type(16)));
typedef short  v8s  __attribute__((ext_vector_type(8)));

__device__ __forceinline__ float sigf(float x) { return 1.0f / (1.0f + __expf(-x)); }
__device__ __forceinline__ float tanhfast(float x) { return 2.0f / (1.0f + __expf(-2.0f * x)) - 1.0f; }
__device__ __forceinline__ u16 f2bf(float f) {
    u32 x = __float_as_uint(f);
    u32 r = (x + 0x7fffu + ((x >> 16) & 1u)) >> 16;   // RNE
    return (u16)r;
}

// ---------------------------------------------------------------------
// Conv-as-MFMA constants (verified R4)
// ---------------------------------------------------------------------
#define KE        19
#define SLAB      2048
#define G0_OFF    0
#define G1_OFF    (3 * KE * SLAB)
#define G2_OFF    (7 * KE * SLAB)
#define WKR_TOT   (12 * KE * SLAB)
#define XSTR      312

__global__ __launch_bounds__(256) void k_cprep(const float* __restrict__ w3,
                                               const float* __restrict__ w4,
                                               const float* __restrict__ w5,
                                               u16* __restrict__ wkr) {
    const int gid = blockIdx.x * 256 + threadIdx.x;
    int g, rem;
    if (gid < G1_OFF)      { g = 0; rem = gid; }
    else if (gid < G2_OFF) { g = 1; rem = gid - G1_OFF; }
    else                   { g = 2; rem = gid - G2_OFF; }
    const int fs = 3 + g;
    const int j  = rem & 7;
    const int q  = (rem >> 3) & 1;
    const int f  = (rem >> 4) & 127;
    const int t  = rem >> 11;
    const int ke = t % KE;
    const int kk = t / KE;
    const int e  = ke * 16 + q * 8 + j;
    float v = 0.0f;
    if (f < 100 && e < 300) {
        const float* w = (g == 0) ? w3 : (g == 1) ? w4 : w5;
        v = w[((size_t)f * 300 + e) * fs + kk];
    }
    wkr[gid] = f2bf(v);
}

// =====================================================================
// K1: conv via MFMA — R11: branch-free phased K-loop + register
// double-buffered B-fragment prefetch (hides L2 latency). MFMA order
// per accumulator unchanged -> bit-identical output to R4's version.
// =====================================================================
__global__ __launch_bounds__(384) void k_conv_mfma(const int* __restrict__ dlg,
                                                   const float* __restrict__ emb,
                                                   const u16* __restrict__ wkr,
                                                   const float* __restrict__ b3,
                                                   const float* __restrict__ b4,
                                                   const float* __restrict__ b5,
                                                   float* __restrict__ feat) {
    __shared__ u16 xT[104 * XSTR];
    __shared__ int toks[96];
    const int u2  = blockIdx.x;
    const int tid = threadIdx.x;
    if (tid < 96) toks[tid] = dlg[u2 * 96 + tid];
    __syncthreads();
    for (int i = tid; i < 96 * 75; i += 384) {
        int t  = i / 75;
        int e4 = i - t * 75;
        int utt = (t >= 48);
        int row = utt * 52 + (t - utt * 48);
        float4 v = *(const float4*)(emb + (size_t)toks[t] * 300 + e4 * 4);
        uint2 o;
        o.x = (u32)f2bf(v.x) | ((u32)f2bf(v.y) << 16);
        o.y = (u32)f2bf(v.z) | ((u32)f2bf(v.w) << 16);
        *(uint2*)&xT[row * XSTR + e4 * 4] = o;
    }
    for (int i = tid; i < 8 * (XSTR / 2); i += 384) {
        int r = i / (XSTR / 2);
        int c = i - r * (XSTR / 2);
        int row = (r < 4) ? (48 + r) : (96 + r - 4);
        *(u32*)&xT[row * XSTR + c * 2] = 0;
    }
    __syncthreads();

    const int wv   = tid >> 6;
    const int lane = tid & 63;
    const int m    = lane & 31;
    const int q    = lane >> 5;

    int abase[3];
#pragma unroll
    for (int mt = 0; mt < 3; ++mt) {
        int r = mt * 32 + m;
        int utt = (r >= 48);
        int p = r - utt * 48;
        abase[mt] = (utt * 52 + p) * XSTR + q * 8;
    }

    int gA, ntA, gB, ntB, kkA, kkB;
    if (wv < 4) { gA = 0; ntA = wv; gB = 2; ntB = wv; kkA = 3; kkB = 5; }
    else        { gA = 1; ntA = (wv - 4) * 2; gB = 1; ntB = ntA + 1; kkA = 4; kkB = 4; }
    const int goffA = (gA == 0) ? G0_OFF : (gA == 1) ? G1_OFF : G2_OFF;
    const int goffB = (gB == 0) ? G0_OFF : (gB == 1) ? G1_OFF : G2_OFF;
    const u16* wA = wkr + goffA + ((ntA * 32 + m) * 2 + q) * 8;
    const u16* wB = wkr + goffB + ((ntB * 32 + m) * 2 + q) * 8;

    v16f accA[3], accB[3];
#pragma unroll
    for (int mt = 0; mt < 3; ++mt) {
#pragma unroll
        for (int r = 0; r < 16; ++r) { accA[mt][r] = 0.0f; accB[mt][r] = 0.0f; }
    }

    // phase 1: kk in [0, kmin) — both groups, branch-free, B-frags
    // double-buffered in registers (prefetch slab n+1 while using slab n).
    const int kmin = (kkA < kkB) ? kkA : kkB;   // waves0-3: 3, waves4-5: 4
    const u16* pA = wA;
    const u16* pB = wB;
    v8s bfA = *(const v8s*)pA;
    v8s bfB = *(const v8s*)pB;
    for (int kk = 0; kk < kmin; ++kk) {
        const int xshift = kk * XSTR;
        for (int ke = 0; ke < KE; ++ke) {
            v8s cA = bfA, cB = bfB;
            pA += SLAB; pB += SLAB;
            bfA = *(const v8s*)pA;             // prefetch (harmless overread at end)
            bfB = *(const v8s*)pB;
            const int xcol = xshift + ke * 16;
#pragma unroll
            for (int mt = 0; mt < 3; ++mt) {
                v8s af = *(const v8s*)&xT[abase[mt] + xcol];
                accA[mt] = __builtin_amdgcn_mfma_f32_32x32x16_bf16(af, cA, accA[mt], 0, 0, 0);
                accB[mt] = __builtin_amdgcn_mfma_f32_32x32x16_bf16(af, cB, accB[mt], 0, 0, 0);
            }
        }
    }
    // phase 2: kk in [kmin, kkB) — group B only (waves 0-3: kk=3,4)
    for (int kk = kmin; kk < kkB; ++kk) {
        const int xshift = kk * XSTR;
        for (int ke = 0; ke < KE; ++ke) {
            v8s cB = bfB;
            pB += SLAB;
            bfB = *(const v8s*)pB;
            const int xcol = xshift + ke * 16;
#pragma unroll
            for (int mt = 0; mt < 3; ++mt) {
                v8s af = *(const v8s*)&xT[abase[mt] + xcol];
                accB[mt] = __builtin_amdgcn_mfma_f32_32x32x16_bf16(af, cB, accB[mt], 0, 0, 0);
            }
        }
    }

    const int PP[3] = {46, 45, 44};
#pragma unroll
    for (int which = 0; which < 2; ++which) {
        const int g  = which ? gB : gA;
        const int nt = which ? ntB : ntA;
        const v16f* acc = which ? accB : accA;
        const float* bg = (g == 0) ? b3 : (g == 1) ? b4 : b5;
        const int f = nt * 32 + m;
        const float bias = (f < 100) ? bg[f] : 0.0f;
        const int Pg = PP[g];
        float v0 = -1e30f, v1 = -1e30f;
#pragma unroll
        for (int mt = 0; mt < 3; ++mt) {
#pragma unroll
            for (int reg = 0; reg < 16; ++reg) {
                int row = (reg & 3) + 8 * (reg >> 2) + 4 * q;
                int r = mt * 32 + row;
                int utt = (r >= 48);
                int p = r - utt * 48;
                if (p < Pg) {
                    float val = acc[mt][reg] + bias;
                    if (utt) v1 = fmaxf(v1, val); else v0 = fmaxf(v0, val);
                }
            }
        }
        v0 = fmaxf(v0, __shfl_xor(v0, 32, 64));
        v1 = fmaxf(v1, __shfl_xor(v1, 32, 64));
        if (q == 0 && f < 100) {
            feat[((size_t)(u2 * 2 + 0)) * 300 + g * 100 + f] = fmaxf(0.0f, v0);
            feat[((size_t)(u2 * 2 + 1)) * 300 + g * 100 + f] = fmaxf(0.0f, v1);
        }
    }
}

// =====================================================================
// K2: xg GEMM; output in MFMA C-fragment order (unchanged)
// =====================================================================
__global__ __launch_bounds__(256) void k_xg(const float* __restrict__ feat,
                                            const float* __restrict__ wih_f, const float* __restrict__ bih_f,
                                            const float* __restrict__ bhh_f,
                                            const float* __restrict__ wih_r, const float* __restrict__ bih_r,
                                            const float* __restrict__ bhh_r,
                                            float* __restrict__ xgF) {
    __shared__ float fls[300 * 36];
    const int bx  = blockIdx.x;
    const int dir = bx >> 8;
    const int t   = (bx >> 2) & 63;
    const int gc  = bx & 3;
    const int tid = threadIdx.x;
    for (int i = tid; i < 32 * 300; i += 256) {
        int b = i / 300;
        int d = i - b * 300;
        fls[d * 36 + b] = feat[((size_t)b * 64 + t) * 300 + d];
    }
    __syncthreads();
    const int g = gc * 256 + tid;
    const float* wih = dir ? wih_r : wih_f;
    const float* bih = dir ? bih_r : bih_f;
    const float* bhh = dir ? bhh_r : bhh_f;
    const float* wr  = wih + (size_t)g * 300;
    const float bias = bih[g] + bhh[g];
    float acc[32];
#pragma unroll
    for (int b = 0; b < 32; ++b) acc[b] = 0.0f;
    for (int d = 0; d < 300; d += 4) {
        float4 wv = *(const float4*)(wr + d);
#pragma unroll
        for (int j = 0; j < 4; ++j) {
            float w = (j == 0) ? wv.x : (j == 1) ? wv.y : (j == 2) ? wv.z : wv.w;
            const float* r = &fls[(d + j) * 36];
#pragma unroll
            for (int bq = 0; bq < 8; ++bq) {
                float4 x = *(const float4*)(r + bq * 4);
                acc[bq * 4 + 0] = fmaf(w, x.x, acc[bq * 4 + 0]);
                acc[bq * 4 + 1] = fmaf(w, x.y, acc[bq * 4 + 1]);
                acc[bq * 4 + 2] = fmaf(w, x.z, acc[bq * 4 + 2]);
                acc[bq * 4 + 3] = fmaf(w, x.w, acc[bq * 4 + 3]);
            }
        }
    }
    const int jj      = tid;
    const int js      = jj >> 6;
    const int n_local = ((jj & 63) << 2) | gc;
    const int nt      = n_local >> 5;
    const int lane_lo = n_local & 31;
    float* base = xgF + (((size_t)(dir * 64 + t) * 32) + js * 8 + nt) * 1024;
#pragma unroll
    for (int b = 0; b < 32; ++b) {
        int q    = (b >> 2) & 1;
        int reg  = (b & 3) + ((b >> 3) << 2);
        base[reg * 64 + lane_lo + (q << 5)] = acc[b] + bias;
    }
}

// =====================================================================
// K_prep3: w_hh -> MFMA B-fragment shards (unchanged)
// =====================================================================
__global__ __launch_bounds__(256) void k_prep3(const float* __restrict__ whh_f,
                                               const float* __restrict__ whh_r,
                                               u16* __restrict__ wpk3) {
    const int gid  = blockIdx.x * 256 + threadIdx.x;    // [0, 524288)
    const int j    = gid & 7;
    const int lane = (gid >> 3) & 63;
    const int kt   = (gid >> 9) & 15;
    const int nt   = (gid >> 13) & 7;
    const int js   = (gid >> 16) & 3;
    const int dir  = (gid >> 18) & 1;
    const int n_local = nt * 32 + (lane & 31);
    const int jjl  = n_local >> 2;
    const int gate = n_local & 3;
    const int k    = kt * 16 + (lane >> 5) * 8 + j;
    const int row  = gate * 256 + js * 64 + jjl;
    const float* whh = dir ? whh_r : whh_f;
    wpk3[gid] = f2bf(whh[(size_t)row * 256 + k]);
}

// k_init: zero the 8 sentinels
__global__ __launch_bounds__(64) void k_init(u32* __restrict__ sent) {
    if (threadIdx.x < 8) sent[threadIdx.x] = 0u;
}

// =====================================================================
// K3 v5 (R9-proven, verbatim): LSTM, 8 blocks (2 dir x 4 js), MFMA,
// sentinel + bulk exchange. 245.8 us measured, absmax 0.0117.
// =====================================================================
__global__ __launch_bounds__(512) void k_lstm3(const u16* __restrict__ wpk3,
                                               const float* __restrict__ xgF,
                                               u64* __restrict__ hx,
                                               u32* __restrict__ sent,
                                               float* __restrict__ hseq) {
    __shared__ u32   hbuf[32 * 132];          // h as bf16-pairs, row stride 132 dw
    __shared__ float gbuf[32 * 276];          // gate preacts
    const int dir = blockIdx.x >> 2;
    const int js  = blockIdx.x & 3;
    const int tid = threadIdx.x;
    const int w   = tid >> 6;                 // n-tile 0..7
    const int l   = tid & 63;
    const int m   = l & 31;
    const int q   = l >> 5;

    v8s Bf[16];
    {
        const u16* wb = wpk3 + ((((size_t)dir * 4 + js) * 8 + w) * 16) * 512 + (size_t)l * 8;
#pragma unroll
        for (int kt = 0; kt < 16; ++kt) Bf[kt] = *(const v8s*)(wb + kt * 512);
    }

    const int eb  = tid & 31;
    const int ejb = tid >> 5;
    float cst[4], hval[4];
#pragma unroll
    for (int c2 = 0; c2 < 4; ++c2) { cst[c2] = 0.0f; hval[c2] = 0.0f; }

    float* hout = hseq + (size_t)dir * 64 * 32 * 256;
    u64* hx_d   = hx + (size_t)dir * 2 * 2048;
    const int peer = (tid < 3) ? (dir * 4 + tid + (tid >= js ? 1 : 0)) : 0;

    for (int s = 0; s < 64; ++s) {
        const int t = dir ? (63 - s) : s;
        v16f acc;
        const float* xb = xgF + (((size_t)(dir * 64 + t) * 32) + js * 8 + w) * 1024 + l;
#pragma unroll
        for (int r = 0; r < 16; ++r) acc[r] = xb[r * 64];

        if (s > 0 && tid < 3) {
            u32 guard = 0;
            while (__hip_atomic_load(&sent[peer], __ATOMIC_RELAXED,
                                     __HIP_MEMORY_SCOPE_AGENT) < (u32)s) {
                __builtin_amdgcn_s_sleep(1);
                if (++guard > (1u << 25)) break;
            }
        }
        __syncthreads();

        if (s > 0) {
            const u64* hxs = hx_d + (size_t)(s & 1) * 2048;
#pragma unroll
            for (int i = 0; i < 3; ++i) {
                int flat = i * 512 + tid;
                int b    = flat / 48;
                int r    = flat - b * 48;
                int q64  = r + (r >= js * 16 ? 16 : 0);
                u64 v = __hip_atomic_load(&hxs[b * 64 + q64],
                                          __ATOMIC_RELAXED, __HIP_MEMORY_SCOPE_AGENT);
                *(u64*)&hbuf[b * 132 + q64 * 2] = v;
            }
        } else {
            for (int i = tid; i < 32 * 132; i += 512) hbuf[i] = 0u;
        }
        {
            u64 pk = (u64)f2bf(hval[0]) | ((u64)f2bf(hval[1]) << 16)
                   | ((u64)f2bf(hval[2]) << 32) | ((u64)f2bf(hval[3]) << 48);
            *(u64*)&hbuf[eb * 132 + (js * 16 + ejb) * 2] = pk;
        }
        __syncthreads();

#pragma unroll
        for (int kt = 0; kt < 16; ++kt) {
            v8s af = *(const v8s*)&hbuf[m * 132 + kt * 8 + q * 4];
            acc = __builtin_amdgcn_mfma_f32_32x32x16_bf16(af, Bf[kt], acc, 0, 0, 0);
        }

#pragma unroll
        for (int r = 0; r < 16; ++r) {
            int row = (r & 3) + 8 * (r >> 2) + 4 * q;
            gbuf[row * 276 + w * 32 + m] = acc[r];
        }
        __syncthreads();

        {
            const float* gb = &gbuf[eb * 276 + ejb * 16];
#pragma unroll
            for (int c2 = 0; c2 < 4; ++c2) {
                float4 gv = *(const float4*)(gb + c2 * 4);
                float i_ = sigf(gv.x), f_ = sigf(gv.y);
                float g_ = tanhfast(gv.z), o_ = sigf(gv.w);
                cst[c2] = f_ * cst[c2] + i_ * g_;
                hval[c2] = o_ * tanhfast(cst[c2]);
            }
        }
        {
            float4 hv4 = make_float4(hval[0], hval[1], hval[2], hval[3]);
            *(float4*)&hout[((size_t)t * 32 + eb) * 256 + js * 64 + ejb * 4] = hv4;
            u64 pk = (u64)f2bf(hval[0]) | ((u64)f2bf(hval[1]) << 16)
                   | ((u64)f2bf(hval[2]) << 32) | ((u64)f2bf(hval[3]) << 48);
            u64* hxn = hx_d + (size_t)((s + 1) & 1) * 2048;
            __hip_atomic_store(&hxn[eb * 64 + js * 16 + ejb], pk,
                               __ATOMIC_RELAXED, __HIP_MEMORY_SCOPE_AGENT);
        }
        __syncthreads();
        if (tid == 0) {
            __hip_atomic_store(&sent[dir * 4 + js], (u32)(s + 1),
                               __ATOMIC_RELAXED, __HIP_MEMORY_SCOPE_AGENT);
        }
    }
}

// =====================================================================
// K4: head (unchanged)
// =====================================================================
__global__ __launch_bounds__(256) void k_head(const float* __restrict__ hseq,
                                              const float* __restrict__ hw,
                                              const float* __restrict__ hb,
                                              float* __restrict__ out) {
    const int id = blockIdx.x * 256 + threadIdx.x;
    const int o  = id & 31;
    const int u  = id >> 5;
    const int b  = u >> 6, t = u & 63;
    const float* pf = hseq + ((size_t)t * 32 + b) * 256;
    const float* pr = hseq + (size_t)64 * 32 * 256 + ((size_t)t * 32 + b) * 256;
    const float* wo = hw + (size_t)o * 512;
    float acc = hb[o];
    for (int j = 0; j < 256; j += 4) {
        float4 wa = *(const float4*)(wo + j);
        float4 wb = *(const float4*)(wo + 256 + j);
        float4 fa = *(const float4*)(pf + j);
        float4 fb = *(const float4*)(pr + j);
        acc = fmaf(wa.x, fa.x, acc); acc = fmaf(wa.y, fa.y, acc);
        acc = fmaf(wa.z, fa.z, acc); acc = fmaf(wa.w, fa.w, acc);
        acc = fmaf(wb.x, fb.x, acc); acc = fmaf(wb.y, fb.y, acc);
        acc = fmaf(wb.z, fb.z, acc); acc = fmaf(wb.w, fb.w, acc);
    }
    out[id] = sigf(acc);
}

// =====================================================================
extern "C" void kernel_launch(void* const* d_in, const int* in_sizes, int n_in,
                              void* d_out, int out_size, void* d_ws, size_t ws_size,
                              hipStream_t stream) {
    const int*   dlg   = (const int*)d_in[0];
    const float* emb   = (const float*)d_in[1];
    const float* w3    = (const float*)d_in[2];  const float* b3    = (const float*)d_in[3];
    const float* w4    = (const float*)d_in[4];  const float* b4    = (const float*)d_in[5];
    const float* w5    = (const float*)d_in[6];  const float* b5    = (const float*)d_in[7];
    const float* wih_f = (const float*)d_in[8];  const float* whh_f = (const float*)d_in[9];
    const float* bih_f = (const float*)d_in[10]; const float* bhh_f = (const float*)d_in[11];
    const float* wih_r = (const float*)d_in[12]; const float* whh_r = (const float*)d_in[13];
    const float* bih_r = (const float*)d_in[14]; const float* bhh_r = (const float*)d_in[15];
    const float* hw    = (const float*)d_in[16]; const float* hb    = (const float*)d_in[17];
    float* out = (float*)d_out;

    float* f     = (float*)d_ws;
    float* feat  = f;                         // 614400
    float* xgF   = f + 614400;                // 4194304
    float* hseq  = f + 4808704;               // 1048576
    u16*   wkr   = (u16*)(f + 5857280);       // 466944 u16
    u16*   wpk3  = (u16*)(f + 6090752);       // 524288 u16
    u64*   hx    = (u64*)(f + 6352896);       // 8192 u64 (2 dir x 2 slot x 2048)
    u32*   sent  = (u32*)(f + 6369280);       // 8 u32
    // total ~25.5 MB

    hipLaunchKernelGGL(k_init, dim3(1), dim3(64), 0, stream, sent);
    hipLaunchKernelGGL(k_cprep, dim3(WKR_TOT / 256), dim3(256), 0, stream,
                       w3, w4, w5, wkr);
    hipLaunchKernelGGL(k_prep3, dim3(2048), dim3(256), 0, stream,
                       whh_f, whh_r, wpk3);
    hipLaunchKernelGGL(k_conv_mfma, dim3(1024), dim3(384), 0, stream,
                       dlg, emb, wkr, b3, b4, b5, feat);
    hipLaunchKernelGGL(k_xg, dim3(512), dim3(256), 0, stream,
                       feat, wih_f, bih_f, bhh_f, wih_r, bih_r, bhh_r, xgF);
    hipLaunchKernelGGL(k_lstm3, dim3(8), dim3(512), 0, stream,
                       wpk3, xgF, hx, sent, hseq);
    hipLaunchKernelGGL(k_head, dim3(256), dim3(256), 0, stream,
                       hseq, hw, hb, out);
}